// Round 5
// baseline (131.120 us; speedup 1.0000x reference)
//
#include <hip/hip_runtime.h>
#include <hip/hip_bf16.h>

#define BATCH   32
#define TLEN    128000
#define FGAIN   1000
#define ORDER   26
#define WLEN    512
#define HOP     128
#define PAD     192                 // (512-128)/2
#define TPAD    (TLEN + 2*PAD)      // 128384 padded length
#define NFRAME  1000
#define NTOT    (BATCH*NFRAME)      // 32000 frames total

#define CHUNK   64                  // frames per k_lpc block (= 1 wave)
#define NCHUNK  ((NFRAME + CHUNK - 1) / CHUNK)   // 16 (15 full + tail of 40)
#define XS_SPAN (CHUNK*HOP + WLEN - HOP)         // 8576 floats staged per block
#define XS_LDS  8656                // 8576 + 67 pad + slack

// ---------------------------------------------------------------------------
// Kernel 1: exg_padded[b][p] = (PAD <= p < PAD+TLEN) ? ex[b][p-PAD] * ug(b, p-PAD) : 0
// ug = linear upsample of gain (F=1000 -> T=128000, hop=128).
// src arithmetic exact in f32 -> i0/w match the JAX reference bit-for-bit.
// ---------------------------------------------------------------------------
__global__ __launch_bounds__(256) void k_exg(const float* __restrict__ ex,
                                             const float* __restrict__ gain,
                                             float* __restrict__ exg) {
  int gid = blockIdx.x * 256 + threadIdx.x;   // one thread per 4 elements
  const int total4 = BATCH * TPAD / 4;
  if (gid >= total4) return;
  int idx = gid * 4;
  int b  = idx / TPAD;
  int r0 = idx - b * TPAD;
  const float* __restrict__ gr  = gain + b * FGAIN;
  const float* __restrict__ exr = ex + (size_t)b * TLEN;
  float v[4];
#pragma unroll
  for (int c = 0; c < 4; ++c) {
    int j = r0 + c - PAD;
    float val = 0.0f;
    if (j >= 0 && j < TLEN) {
      float src = ((float)j + 0.5f) * (1.0f / (float)HOP) - 0.5f;
      src = fminf(fmaxf(src, 0.0f), (float)(FGAIN - 1));
      int   i0 = (int)src;                 // floor (src >= 0)
      float w  = src - (float)i0;
      int   i1 = (i0 < FGAIN - 1) ? i0 + 1 : FGAIN - 1;
      float g  = gr[i0] * (1.0f - w) + gr[i1] * w;
      val = exr[j] * g;
    }
    v[c] = val;
  }
  float4 o = make_float4(v[0], v[1], v[2], v[3]);
  *reinterpret_cast<float4*>(exg + idx) = o;
}

// ---------------------------------------------------------------------------
// Kernel 2: per-frame order-26 IIR synthesis. One frame per lane, one wave
// per block, 64 consecutive frames of one batch row per block.
//
// R2: scattered-VMEM-bound (64 lines per wave64 mem op). R3 fixed stores/loads
// to float4 superblocks. R4 (this): adjacent lanes' x-windows overlap 75%, so
// stage the block's x union (8576 floats, 34.6 KB) into LDS ONCE, coalesced,
// with +1-per-128 padding (stride 129): per-superblock ds_read_b32 banks are
// (lane + const) % 32 -> 2 lanes/bank, conflict-free. Kills the 4x redundant
// scattered x loads; remaining TA work is the fw stores only.
// Tap 0 applied LAST so the cross-step critical path is a single FMA.
// ---------------------------------------------------------------------------
__global__ __launch_bounds__(64) void k_lpc(const float* __restrict__ exg,
                                            const float* __restrict__ acoef,
                                            float* __restrict__ fw) {
  __shared__ float xs[XS_LDS];

  const int lane = threadIdx.x;               // 0..63
  const int n0   = blockIdx.x * CHUNK;        // first frame of this chunk
  const int b    = blockIdx.y;                // batch row
  const float* __restrict__ xrow = exg + (size_t)b * TPAD;

  // ---- stage x union into LDS (coalesced float4, zero-fill OOB tail) ----
  for (int i = lane; i < XS_SPAN / 4; i += 64) {
    int s = 4 * i;
    int g = n0 * HOP + s;                     // offset in padded row
    float4 v = make_float4(0.f, 0.f, 0.f, 0.f);
    if (g < TPAD)                             // g%4==0, TPAD%4==0 -> all-or-none
      v = *reinterpret_cast<const float4*>(xrow + g);
    int base = s + (s >> 7);                  // +1 pad per 128 (s%128<=124)
    xs[base + 0] = v.x;  xs[base + 1] = v.y;
    xs[base + 2] = v.z;  xs[base + 3] = v.w;
  }
  __syncthreads();

  // ---- per-lane frame setup ----
  const bool valid = (n0 + lane) < NFRAME;
  int f = b * NFRAME + n0 + lane;
  int f_cl = f < NTOT ? f : NTOT - 1;         // clamp for tail-chunk dummies
  const float* __restrict__ ap = acoef + (size_t)f_cl * ORDER;
  float* __restrict__ op = fw + (size_t)f * WLEN;   // only touched if valid

  float a[ORDER], h[ORDER];
#pragma unroll
  for (int q = 0; q < 13; ++q) {              // 13 x float2 (8B-aligned base)
    float2 v = *reinterpret_cast<const float2*>(ap + 2 * q);
    a[2 * q] = v.x;  a[2 * q + 1] = v.y;
  }
#pragma unroll
  for (int k = 0; k < ORDER; ++k) h[k] = 0.0f;

  float buf[52];

  // Invariant at step s (t % 26 == 0): h[m] holds the newest y at time
  // congruent to m (mod 26). Need y[t+s-1-k] -> slot ((s-1-k) mod 26).
  // All indices below are compile-time constants after unrolling.
#define LPC_STEP(s) {                                                      \
    float xv = buf[(s)];                                                   \
    float p0 = xv, p1 = 0.f, p2 = 0.f, p3 = 0.f;                           \
    _Pragma("unroll")                                                      \
    for (int k = 1; k < ORDER; ++k) {                                      \
      float hv = h[((s) - 1 - k + 2 * ORDER) % ORDER];                     \
      int sel = k & 3;                                                     \
      if      (sel == 0) p0 -= a[k] * hv;                                  \
      else if (sel == 1) p1 -= a[k] * hv;                                  \
      else if (sel == 2) p2 -= a[k] * hv;                                  \
      else               p3 -= a[k] * hv;                                  \
    }                                                                      \
    float rest = (p0 + p1) + (p2 + p3);                                    \
    float y = rest - a[0] * h[((s) + ORDER - 1) % ORDER];                  \
    h[(s) % ORDER] = y;                                                    \
    buf[(s)] = y;                                                          \
  }

  // lane's frame occupies LDS positions lane*128 + u, u in [0,512);
  // padded index = lane*129 + u + (u>>7). Per-read banks (lane+C)%32: free.
#define LOAD_BUF(nq) {                                                     \
    _Pragma("unroll")                                                      \
    for (int q = 0; q < (nq); ++q) {                                       \
      int u = t + 4 * q;                                                   \
      int base = lane * 129 + u + (u >> 7);                                \
      buf[4 * q + 0] = xs[base + 0];                                       \
      buf[4 * q + 1] = xs[base + 1];                                       \
      buf[4 * q + 2] = xs[base + 2];                                       \
      buf[4 * q + 3] = xs[base + 3];                                       \
    }                                                                      \
  }

  int t = 0;
  for (int sb = 0; sb < 9; ++sb) {            // 9 * 52 = 468
    LOAD_BUF(13)
#pragma unroll
    for (int s = 0; s < 52; ++s) {
      LPC_STEP(s)
    }
    if (valid) {
#pragma unroll
      for (int q = 0; q < 13; ++q) {
        float4 v = make_float4(buf[4 * q + 0], buf[4 * q + 1],
                               buf[4 * q + 2], buf[4 * q + 3]);
        *reinterpret_cast<float4*>(op + t + 4 * q) = v;
      }
    }
    t += 52;
  }
  // epilogue: t = 468 (468 % 26 == 0), 44 remaining steps = 11 x float4
  LOAD_BUF(11)
#pragma unroll
  for (int s = 0; s < 44; ++s) {
    LPC_STEP(s)
  }
  if (valid) {
#pragma unroll
    for (int q = 0; q < 11; ++q) {
      float4 v = make_float4(buf[4 * q + 0], buf[4 * q + 1],
                             buf[4 * q + 2], buf[4 * q + 3]);
      *reinterpret_cast<float4*>(op + t + 4 * q) = v;
    }
  }
#undef LPC_STEP
#undef LOAD_BUF
}

// ---------------------------------------------------------------------------
// Kernel 3: windowed overlap-add + normalization.
// out[b][j] = ( sum_n fw[b][n][p-128n] * win[p-128n] ) / ( sum_n win[p-128n] ),
// p = j + PAD. 4 outputs per thread; w0 is always a multiple of 4 so every
// frame covers all-4-or-none samples and all float4 accesses are 16B-aligned.
// ---------------------------------------------------------------------------
__global__ __launch_bounds__(256) void k_ola(const float* __restrict__ fw,
                                             const float* __restrict__ win,
                                             float* __restrict__ out) {
  int gid = blockIdx.x * 256 + threadIdx.x;   // one thread per 4 outputs
  const int total4 = BATCH * TLEN / 4;
  if (gid >= total4) return;
  int idx = gid * 4;
  int b  = idx / TLEN;
  int j0 = idx - b * TLEN;
  int p0 = j0 + PAD;

  // frames n with 0 <= p0-128n <= 508:  ceil((p0-508)/128) == (p0-381)/128
  int lo = (p0 - 381) / HOP;
  if (lo < 0) lo = 0;
  int hi = p0 / HOP;
  if (hi > NFRAME - 1) hi = NFRAME - 1;

  float ax = 0.f, ay = 0.f, az = 0.f, aw = 0.f;
  float nx = 0.f, ny = 0.f, nz = 0.f, nw = 0.f;
  for (int n = lo; n <= hi; ++n) {
    int w0 = p0 - n * HOP;       // 0..508, multiple of 4
    const float4 fv = *reinterpret_cast<const float4*>(fw + ((size_t)b * NFRAME + n) * WLEN + w0);
    const float4 wv = *reinterpret_cast<const float4*>(win + w0);
    ax += fv.x * wv.x;  ay += fv.y * wv.y;  az += fv.z * wv.z;  aw += fv.w * wv.w;
    nx += wv.x;         ny += wv.y;         nz += wv.z;         nw += wv.w;
  }
  float4 o = make_float4(ax / nx, ay / ny, az / nz, aw / nw);
  *reinterpret_cast<float4*>(out + idx) = o;
}

// ---------------------------------------------------------------------------
extern "C" void kernel_launch(void* const* d_in, const int* in_sizes, int n_in,
                              void* d_out, int out_size, void* d_ws, size_t ws_size,
                              hipStream_t stream) {
  const float* ex   = (const float*)d_in[0];   // [32][128000]
  const float* gain = (const float*)d_in[1];   // [32][1000]
  const float* a    = (const float*)d_in[2];   // [32][1000][26]
  const float* win  = (const float*)d_in[3];   // [512]
  // d_in[4] = hop_length (=128, compile-time constant here)
  float* outp = (float*)d_out;                 // [32][128000]

  // workspace layout: exg_padded [32][128384] f32, then fw [32][1000][512] f32
  float* exg = (float*)d_ws;
  float* fw  = exg + (size_t)BATCH * TPAD;     // byte offset 16,433,152 (16B aligned)
  // total ws usage: (4,108,288 + 16,384,000) * 4 B ~= 82 MB

  {
    int total4 = BATCH * TPAD / 4;
    int blocks = (total4 + 255) / 256;
    hipLaunchKernelGGL(k_exg, dim3(blocks), dim3(256), 0, stream, ex, gain, exg);
  }
  {
    hipLaunchKernelGGL(k_lpc, dim3(NCHUNK, BATCH), dim3(64), 0, stream, exg, a, fw);
  }
  {
    int total4 = BATCH * TLEN / 4;
    int blocks = (total4 + 255) / 256;
    hipLaunchKernelGGL(k_ola, dim3(blocks), dim3(256), 0, stream, fw, win, outp);
  }
}